// Round 11
// baseline (1224.717 us; speedup 1.0000x reference)
//
#include <hip/hip_runtime.h>
#include <hip/hip_bf16.h>

#define N_NODES   100000
#define N_EDGES   800000
#define NUM_GRAPHS 512
#define IN_DIM    16
#define HID       64
#define MLP_H     32
#define EPS       1e-5f
#define TPB       256
#define SCAN_B    1024
#define NCHUNK    ((N_NODES + SCAN_B - 1) / SCAN_B)   // 98
#define GSB       2048
#define NWAVES    (GSB * 4)                           // 8192
#define EPAD_MAX  1100000
#define PER_WP    ((EPAD_MAX + NWAVES - 1) / NWAVES)  // 135
#define NMAP_MAX  (EPAD_MAX/4 + 8)
#define NODEBLKS  ((N_NODES + 63) / 64)               // 1563

using nh2   = decltype(__builtin_amdgcn_cvt_pkrtz(0.f, 0.f));  // packed 2x f16
typedef _Float16 f16x8 __attribute__((ext_vector_type(8)));
typedef float    f32x4 __attribute__((ext_vector_type(4)));
typedef int      i32x4 __attribute__((ext_vector_type(4)));

__device__ __forceinline__ nh2 pack2(float a, float b) {
  return __builtin_amdgcn_cvt_pkrtz(a, b);
}
__device__ __forceinline__ float wsum(float v) {
  v += __shfl_xor(v, 1, 64);
  v += __shfl_xor(v, 2, 64);
  v += __shfl_xor(v, 4, 64);
  v += __shfl_xor(v, 8, 64);
  v += __shfl_xor(v, 16, 64);
  v += __shfl_xor(v, 32, 64);
  return v;
}

// -------------------- CSR build (padded to multiples of 4 per node) --------------------
__global__ __launch_bounds__(TPB) void k_deg(const int* __restrict__ ei, int* __restrict__ deg) {
  int e = blockIdx.x * TPB + threadIdx.x;
  if (e < N_EDGES) atomicAdd(&deg[ei[N_EDGES + e]], 1);
}

__global__ __launch_bounds__(SCAN_B) void k_scan_part(const int* __restrict__ deg,
                                                      int* __restrict__ partials) {
  __shared__ int red[SCAN_B];
  int i = blockIdx.x * SCAN_B + threadIdx.x;
  red[threadIdx.x] = (i < N_NODES) ? ((deg[i] + 3) & ~3) : 0;
  __syncthreads();
  for (int off = SCAN_B / 2; off > 0; off >>= 1) {
    if (threadIdx.x < off) red[threadIdx.x] += red[threadIdx.x + off];
    __syncthreads();
  }
  if (threadIdx.x == 0) partials[blockIdx.x] = red[0];
}

__global__ void k_scan_mid(int* __restrict__ partials, int* __restrict__ rs_pad) {
  int run = 0;
  for (int b = 0; b < NCHUNK; ++b) { int t = partials[b]; partials[b] = run; run += t; }
  rs_pad[N_NODES] = run;  // == Epad
}

__global__ __launch_bounds__(SCAN_B) void k_scan_fin(const int* __restrict__ deg,
                                                     const int* __restrict__ partials,
                                                     int* __restrict__ rs_pad,
                                                     int* __restrict__ cursor) {
  __shared__ int buf[2][SCAN_B];
  int t = threadIdx.x, i = blockIdx.x * SCAN_B + t;
  int v = (i < N_NODES) ? ((deg[i] + 3) & ~3) : 0;
  buf[0][t] = v;
  __syncthreads();
  int cur = 0;
  for (int off = 1; off < SCAN_B; off <<= 1) {
    int nv = buf[cur][t] + ((t >= off) ? buf[cur][t - off] : 0);
    buf[cur ^ 1][t] = nv; cur ^= 1;
    __syncthreads();
  }
  if (i < N_NODES) {
    int excl = buf[cur][t] - v + partials[blockIdx.x];
    rs_pad[i] = excl;
    cursor[i] = excl;
  }
}

// real edges -> padded slots (first deg slots of node's region), flag=1
__global__ __launch_bounds__(TPB) void k_fill(const int* __restrict__ ei,
                                              const float* __restrict__ ea,
                                              int* __restrict__ cursor,
                                              i32x4* __restrict__ erec) {
  int e = blockIdx.x * TPB + threadIdx.x;
  if (e >= N_EDGES) return;
  int dst = ei[N_EDGES + e];
  int pos = atomicAdd(&cursor[dst], 1);
  i32x4 rec;
  rec[0] = ei[e];
  rec[1] = dst;
  rec[2] = __float_as_int(ea[e]);
  rec[3] = 1;
  erec[pos] = rec;
}

// pad records (flag=0) + nmap[grp] = node | (validcount<<20)
__global__ __launch_bounds__(TPB) void k_pad(const int* __restrict__ deg,
                                             const int* __restrict__ rs_pad,
                                             i32x4* __restrict__ erec,
                                             int* __restrict__ nmap) {
  int n = blockIdx.x * TPB + threadIdx.x;
  if (n >= N_NODES) return;
  int d = deg[n];
  int ps = rs_pad[n];
  int gcnt = (d + 3) >> 2;
  for (int j = 0; j < gcnt; ++j) {
    int vcnt = d - 4 * j; if (vcnt > 4) vcnt = 4;
    nmap[(ps >> 2) + j] = n | (vcnt << 20);
  }
  int pd = gcnt * 4;
  i32x4 rec; rec[0] = 0; rec[1] = n; rec[2] = 0; rec[3] = 0;
  for (int s = d; s < pd; ++s) erec[ps + s] = rec;
}

// -------------------- input projection --------------------
__global__ __launch_bounds__(TPB) void k_lin_in(const float* __restrict__ x,
                                                const float* __restrict__ w,
                                                const float* __restrict__ b,
                                                float* __restrict__ h) {
  int i = blockIdx.x * TPB + threadIdx.x;
  if (i >= N_NODES) return;
  float xi[IN_DIM];
  const float4* xp = reinterpret_cast<const float4*>(x + i * IN_DIM);
#pragma unroll
  for (int q = 0; q < 4; ++q) {
    float4 v = xp[q];
    xi[4*q] = v.x; xi[4*q+1] = v.y; xi[4*q+2] = v.z; xi[4*q+3] = v.w;
  }
  float4* hp = reinterpret_cast<float4*>(h + i * HID);
#pragma unroll
  for (int j4 = 0; j4 < HID/4; ++j4) {
    float o[4];
#pragma unroll
    for (int c = 0; c < 4; ++c) {
      int j = j4*4 + c;
      float acc = b[j];
#pragma unroll
      for (int k = 0; k < IN_DIM; ++k) acc += xi[k] * w[k*HID + j];
      o[c] = acc;
    }
    float4 ov = {o[0], o[1], o[2], o[3]};
    hp[j4] = ov;
  }
}

// -------------------- per-node msg projections, 4-way scalar-part split ---------------
__global__ __launch_bounds__(TPB) void k_pq(const float* __restrict__ h,
                                            const float* __restrict__ w1,
                                            const float* __restrict__ b1,
                                            float* __restrict__ P,
                                            _Float16* __restrict__ Qh) {
  const int part = __builtin_amdgcn_readfirstlane(threadIdx.x >> 6);  // SGPR
  const int lane = threadIdx.x & 63;
  const int i = blockIdx.x * 64 + lane;
  if (i >= N_NODES) return;
  const int jb = (part & 1) * 16;
  const bool isQ = part >= 2;
  const float* wbase = w1 + (isQ ? 64 * MLP_H : 0) + jb;
  float acc[16];
#pragma unroll
  for (int j = 0; j < 16; ++j) acc[j] = isQ ? 0.f : b1[jb + j];
  const float4* hp = reinterpret_cast<const float4*>(h + i * HID);
#pragma unroll 4
  for (int k4 = 0; k4 < 16; ++k4) {
    float4 a = hp[k4];
    const float* wr = wbase + (k4*4) * MLP_H;
#pragma unroll
    for (int j = 0; j < 16; ++j)
      acc[j] += a.x*wr[j] + a.y*wr[MLP_H+j] + a.z*wr[2*MLP_H+j] + a.w*wr[3*MLP_H+j];
  }
  if (!isQ) {
    float4* pp = reinterpret_cast<float4*>(P + i * MLP_H + jb);
#pragma unroll
    for (int c = 0; c < 4; ++c) {
      float4 o = {acc[4*c], acc[4*c+1], acc[4*c+2], acc[4*c+3]};
      pp[c] = o;
    }
  } else {
    i32x4 o0, o1;
#pragma unroll
    for (int c = 0; c < 4; ++c) {
      o0[c] = __builtin_bit_cast(int, pack2(acc[2*c],     acc[2*c+1]));
      o1[c] = __builtin_bit_cast(int, pack2(acc[8+2*c],   acc[8+2*c+1]));
    }
    i32x4* qp = reinterpret_cast<i32x4*>(Qh + i * MLP_H + jb);
    qp[0] = o0; qp[1] = o1;
  }
}

// -------------------- pass 1: gather + z compute + z1h store + BN1 stats (flag-masked) -
// 4 lanes/edge, 16 edges/round, 3-stage pipeline; covers padded records.
__global__ __launch_bounds__(TPB) void k_gather(const float* __restrict__ P,
                                                const _Float16* __restrict__ Qh,
                                                const i32x4* __restrict__ erec,
                                                const float* __restrict__ w1,
                                                const int* __restrict__ rs_pad,
                                                _Float16* __restrict__ z1h,
                                                float* __restrict__ gstat) {
  const int lane = threadIdx.x & 63;
  const int fg   = lane & 3;          // feature octet index
  const int sl   = lane >> 2;         // edge slot within round (0..15)
  const int fb   = fg * 8;
  float wk[8];
#pragma unroll
  for (int i = 0; i < 8; ++i) wk[i] = w1[128 * MLP_H + fb + i];
  float sv[8], qs[8];
#pragma unroll
  for (int i = 0; i < 8; ++i) { sv[i] = 0.f; qs[i] = 0.f; }
  const int Epad = rs_pad[N_NODES];
  const int wv = blockIdx.x * 4 + (threadIdx.x >> 6);
  const int c0 = wv * PER_WP;
  const int c1 = min(c0 + PER_WP, Epad);
  if (c0 < Epad) {
    const int c1m1 = c1 - 1;
    const int rounds = (c1 - c0 + 15) >> 4;
#define EIDX(R) min(c0 + 16*(R) + sl, c1m1)
    i32x4 recA = erec[EIDX(0)];
    i32x4 recB = erec[EIDX(1)];
    i32x4 recH = erec[EIDX(2)];
    f16x8 qA  = *reinterpret_cast<const f16x8*>(Qh + recA[0] * MLP_H + fb);
    f32x4 pA0 = *reinterpret_cast<const f32x4*>(P + recA[1] * MLP_H + fb);
    f32x4 pA1 = *reinterpret_cast<const f32x4*>(P + recA[1] * MLP_H + fb + 4);
    float aA  = __int_as_float(recA[2]);
    int   fA  = recA[3];
    f16x8 qB  = *reinterpret_cast<const f16x8*>(Qh + recB[0] * MLP_H + fb);
    f32x4 pB0 = *reinterpret_cast<const f32x4*>(P + recB[1] * MLP_H + fb);
    f32x4 pB1 = *reinterpret_cast<const f32x4*>(P + recB[1] * MLP_H + fb + 4);
    float aB  = __int_as_float(recB[2]);
    int   fB  = recB[3];
    for (int r = 0; r < rounds; ++r) {
      i32x4 recN = erec[EIDX(r + 3)];
      f16x8 qC  = *reinterpret_cast<const f16x8*>(Qh + recH[0] * MLP_H + fb);
      f32x4 pC0 = *reinterpret_cast<const f32x4*>(P + recH[1] * MLP_H + fb);
      f32x4 pC1 = *reinterpret_cast<const f32x4*>(P + recH[1] * MLP_H + fb + 4);
      float aC  = __int_as_float(recH[2]);
      int   fC  = recH[3];
      const int slot = c0 + 16*r + sl;
      const bool vc = slot < c1;
      float z[8];
#pragma unroll
      for (int i = 0; i < 8; ++i) {
        float pv = (i < 4) ? pA0[i] : pA1[i - 4];
        z[i] = fmaf(aA, wk[i], pv) + (float)qA[i];
      }
      if (vc) {
        i32x4 zp;
#pragma unroll
        for (int ii = 0; ii < 4; ++ii)
          zp[ii] = __builtin_bit_cast(int, pack2(z[2*ii], z[2*ii+1]));
        *reinterpret_cast<i32x4*>(z1h + slot * MLP_H + fb) = zp;
        if (fA) {
#pragma unroll
          for (int i = 0; i < 8; ++i) { sv[i] += z[i]; qs[i] = fmaf(z[i], z[i], qs[i]); }
        }
      }
      qA = qB; pA0 = pB0; pA1 = pB1; aA = aB; fA = fB;
      qB = qC; pB0 = pC0; pB1 = pC1; aB = aC; fB = fC;
      recH = recN;
    }
#undef EIDX
  }
#pragma unroll
  for (int i = 0; i < 8; ++i) {
    sv[i] += __shfl_xor(sv[i], 4, 64);  sv[i] += __shfl_xor(sv[i], 8, 64);
    sv[i] += __shfl_xor(sv[i], 16, 64); sv[i] += __shfl_xor(sv[i], 32, 64);
    qs[i] += __shfl_xor(qs[i], 4, 64);  qs[i] += __shfl_xor(qs[i], 8, 64);
    qs[i] += __shfl_xor(qs[i], 16, 64); qs[i] += __shfl_xor(qs[i], 32, 64);
  }
  __shared__ float ls[4][MLP_H], lq[4][MLP_H];
  const int w = threadIdx.x >> 6;
  if (lane < 4) {
#pragma unroll
    for (int i = 0; i < 8; ++i) { ls[w][fb + i] = sv[i]; lq[w][fb + i] = qs[i]; }
  }
  __syncthreads();
  const int t = threadIdx.x;
  if (t < MLP_H)
    unsafeAtomicAdd(&gstat[t], ls[0][t] + ls[1][t] + ls[2][t] + ls[3][t]);
  else if (t < 2*MLP_H)
    unsafeAtomicAdd(&gstat[t], lq[0][t-MLP_H] + lq[1][t-MLP_H] + lq[2][t-MLP_H] + lq[3][t-MLP_H]);
}

// -------------------- pass 2: dense-tiled MFMA msg2 + atomic aggregate + t-stats ------
// Dense 16-edge tiles over padded slots; row-group g = one node (nmap); grid-stride
// with 1-deep prefetch of z1h/nmap.
__global__ __launch_bounds__(TPB) void k_msgdot(const _Float16* __restrict__ z1h,
                                                const int* __restrict__ nmap,
                                                const int* __restrict__ rs_pad,
                                                const float* __restrict__ gstat_in, // BN1 stats
                                                const float* __restrict__ g1,
                                                const float* __restrict__ be1,
                                                const float* __restrict__ w2,
                                                const float* __restrict__ b2,
                                                float* __restrict__ agg,
                                                float* __restrict__ gstat_out) {
  const int lane = threadIdx.x & 63;
  const int col = lane & 15;
  const int g   = lane >> 4;
  float a1v[8], c1v[8];
#pragma unroll
  for (int i = 0; i < 8; ++i) {
    int kf = g*8 + i;
    float mu = gstat_in[kf] * (1.f / N_EDGES);
    float var = fmaxf(gstat_in[MLP_H + kf] * (1.f / N_EDGES) - mu * mu, 0.f);
    float a = g1[kf] * rsqrtf(var + EPS);
    a1v[i] = a; c1v[i] = be1[kf] - a * mu;
  }
  f16x8 bf0, bf1, bf2, bf3;
#define MKB(BF, C) { i32x4 bw; \
  _Pragma("unroll") for (int ii = 0; ii < 4; ++ii) { \
    nh2 p = pack2(w2[(g*8 + 2*ii) * HID + (C)*16 + col], \
                  w2[(g*8 + 2*ii + 1) * HID + (C)*16 + col]); \
    bw[ii] = __builtin_bit_cast(int, p); } \
  BF = __builtin_bit_cast(f16x8, bw); }
  MKB(bf0, 0) MKB(bf1, 1) MKB(bf2, 2) MKB(bf3, 3)
#undef MKB
  float b2c[4];
#pragma unroll
  for (int c = 0; c < 4; ++c) b2c[c] = b2[c*16 + col];

  float sacc[4] = {0.f,0.f,0.f,0.f}, qacc[4] = {0.f,0.f,0.f,0.f};
  const int Epad = rs_pad[N_NODES];
  const int ntiles = (Epad + 15) >> 4;
  const int wv = blockIdx.x * 4 + (threadIdx.x >> 6);

  if (wv < ntiles) {
    int tile = wv;
    int t0 = tile * 16;
    f16x8 zv = *reinterpret_cast<const f16x8*>(z1h + (t0 + col) * MLP_H + g * 8);
    int nm = nmap[(t0 >> 2) + g];
    while (true) {
      const int tileN = tile + NWAVES;
      const bool hasN = tileN < ntiles;
      const int tN = hasN ? tileN * 16 : t0;
      f16x8 zvN = *reinterpret_cast<const f16x8*>(z1h + (tN + col) * MLP_H + g * 8);
      int nmN = nmap[(tN >> 2) + g];
      // A-prep
      i32x4 aw;
#pragma unroll
      for (int i = 0; i < 4; ++i) {
        float m0 = fmaxf(fmaf(a1v[2*i],   (float)zv[2*i],   c1v[2*i]),   0.f);
        float m1 = fmaxf(fmaf(a1v[2*i+1], (float)zv[2*i+1], c1v[2*i+1]), 0.f);
        aw[i] = __builtin_bit_cast(int, pack2(m0, m1));
      }
      f16x8 af = __builtin_bit_cast(f16x8, aw);
      f32x4 zc = {0.f,0.f,0.f,0.f};
      f32x4 cc0 = __builtin_amdgcn_mfma_f32_16x16x32_f16(af, bf0, zc, 0, 0, 0);
      f32x4 cc1 = __builtin_amdgcn_mfma_f32_16x16x32_f16(af, bf1, zc, 0, 0, 0);
      f32x4 cc2 = __builtin_amdgcn_mfma_f32_16x16x32_f16(af, bf2, zc, 0, 0, 0);
      f32x4 cc3 = __builtin_amdgcn_mfma_f32_16x16x32_f16(af, bf3, zc, 0, 0, 0);
      const int nid = nm & 0xFFFFF;
      const int vcnt = (nm >> 20) & 7;
      bool vld[4];
#pragma unroll
      for (int reg = 0; reg < 4; ++reg) vld[reg] = reg < vcnt;
#define EPI(CC, CI) { \
    float s4 = 0.f; \
    _Pragma("unroll") for (int reg = 0; reg < 4; ++reg) { \
      float tv = fmaxf(CC[reg] + b2c[CI], 0.f); \
      tv = vld[reg] ? tv : 0.f; \
      s4 += tv; qacc[CI] = fmaf(tv, tv, qacc[CI]); } \
    sacc[CI] += s4; \
    unsafeAtomicAdd(&agg[nid * HID + (CI)*16 + col], s4); }
      EPI(cc0, 0) EPI(cc1, 1) EPI(cc2, 2) EPI(cc3, 3)
#undef EPI
      if (!hasN) break;
      tile = tileN; t0 = tN; zv = zvN; nm = nmN;
    }
  }
#pragma unroll
  for (int c = 0; c < 4; ++c) {
    sacc[c] += __shfl_xor(sacc[c], 16, 64);
    sacc[c] += __shfl_xor(sacc[c], 32, 64);
    qacc[c] += __shfl_xor(qacc[c], 16, 64);
    qacc[c] += __shfl_xor(qacc[c], 32, 64);
  }
  __shared__ float ls[4][HID], lq[4][HID];
  const int w = threadIdx.x >> 6;
  if (g == 0) {
#pragma unroll
    for (int c = 0; c < 4; ++c) { ls[w][c*16 + col] = sacc[c]; lq[w][c*16 + col] = qacc[c]; }
  }
  __syncthreads();
  const int t = threadIdx.x;
  if (t < HID)
    unsafeAtomicAdd(&gstat_out[t], ls[0][t] + ls[1][t] + ls[2][t] + ls[3][t]);
  else if (t < 2*HID)
    unsafeAtomicAdd(&gstat_out[t], lq[0][t-HID] + lq[1][t-HID] + lq[2][t-HID] + lq[3][t-HID]);
}

// -------------------- update stage 1, 2-way scalar-part split (no stats) --------------
__global__ __launch_bounds__(TPB) void k_upd1(const float* __restrict__ h,
                                              const float* __restrict__ agg,
                                              const int* __restrict__ deg,
                                              const float* __restrict__ gstat_in, // t stats (E count)
                                              const float* __restrict__ g2,
                                              const float* __restrict__ be2,
                                              const float* __restrict__ w1,
                                              const float* __restrict__ b1,
                                              float* __restrict__ zu1) {
  __shared__ float sa[HID], sc[HID];
  {
    int t = threadIdx.x;
    if (t < HID) {
      float mu = gstat_in[t] * (1.f / N_EDGES);
      float var = fmaxf(gstat_in[HID + t] * (1.f / N_EDGES) - mu * mu, 0.f);
      float a = g2[t] * rsqrtf(var + EPS);
      sa[t] = a; sc[t] = be2[t] - a * mu;
    }
  }
  __syncthreads();
  const int widx = __builtin_amdgcn_readfirstlane(threadIdx.x >> 6);  // SGPR
  const int part = widx & 1;
  const int grp  = blockIdx.x * 2 + (widx >> 1);
  const int lane = threadIdx.x & 63;
  const int jb = part * 16;
  const int i = grp * 64 + lane;
  if (i >= N_NODES) return;
  float acc[16];
#pragma unroll
  for (int j = 0; j < 16; ++j) acc[j] = b1[jb + j];
  const float4* hp = reinterpret_cast<const float4*>(h + i * HID);
#pragma unroll 4
  for (int k4 = 0; k4 < 16; ++k4) {
    float4 a = hp[k4];
    const float* wr = w1 + (k4*4) * MLP_H + jb;
#pragma unroll
    for (int j = 0; j < 16; ++j)
      acc[j] += a.x*wr[j] + a.y*wr[MLP_H+j] + a.z*wr[2*MLP_H+j] + a.w*wr[3*MLP_H+j];
  }
  float degf = (float)deg[i];
  const float4* ap = reinterpret_cast<const float4*>(agg + i * HID);
#pragma unroll 4
  for (int k4 = 0; k4 < 16; ++k4) {
    float4 g4 = ap[k4];
    int k = k4*4;
    float a0 = sa[k]  *g4.x + sc[k]  *degf;
    float a1 = sa[k+1]*g4.y + sc[k+1]*degf;
    float a2 = sa[k+2]*g4.z + sc[k+2]*degf;
    float a3 = sa[k+3]*g4.w + sc[k+3]*degf;
    const float* wr = w1 + (64 + k) * MLP_H + jb;
#pragma unroll
    for (int j = 0; j < 16; ++j)
      acc[j] += a0*wr[j] + a1*wr[MLP_H+j] + a2*wr[2*MLP_H+j] + a3*wr[3*MLP_H+j];
  }
  float4* zp = reinterpret_cast<float4*>(zu1 + i * MLP_H + jb);
#pragma unroll
  for (int c = 0; c < 4; ++c) {
    float4 o = {acc[4*c], acc[4*c+1], acc[4*c+2], acc[4*c+3]};
    zp[c] = o;
  }
}

// -------------------- update stage 2, 2-way scalar-part split (no stats) --------------
__global__ __launch_bounds__(TPB) void k_upd2(const float* __restrict__ zu1,
                                              const float* __restrict__ gstat_in, // zu1 stats (N count)
                                              const float* __restrict__ gu1,
                                              const float* __restrict__ beu1,
                                              const float* __restrict__ w2,
                                              const float* __restrict__ b2,
                                              float* __restrict__ tu) {
  __shared__ float sa[MLP_H], sc[MLP_H];
  {
    int t = threadIdx.x;
    if (t < MLP_H) {
      float mu = gstat_in[t] * (1.f / N_NODES);
      float var = fmaxf(gstat_in[MLP_H + t] * (1.f / N_NODES) - mu * mu, 0.f);
      float a = gu1[t] * rsqrtf(var + EPS);
      sa[t] = a; sc[t] = beu1[t] - a * mu;
    }
  }
  __syncthreads();
  const int widx = __builtin_amdgcn_readfirstlane(threadIdx.x >> 6);  // SGPR
  const int part = widx & 1;
  const int grp  = blockIdx.x * 2 + (widx >> 1);
  const int lane = threadIdx.x & 63;
  const int jb = part * 32;
  const int i = grp * 64 + lane;
  if (i >= N_NODES) return;
  float m1[MLP_H];
  const float4* zp = reinterpret_cast<const float4*>(zu1 + i * MLP_H);
#pragma unroll
  for (int c = 0; c < MLP_H/4; ++c) {
    float4 z = zp[c];
    int kk = 4*c;
    m1[kk]   = fmaxf(sa[kk]  *z.x + sc[kk],   0.f);
    m1[kk+1] = fmaxf(sa[kk+1]*z.y + sc[kk+1], 0.f);
    m1[kk+2] = fmaxf(sa[kk+2]*z.z + sc[kk+2], 0.f);
    m1[kk+3] = fmaxf(sa[kk+3]*z.w + sc[kk+3], 0.f);
  }
#pragma unroll
  for (int j4 = 0; j4 < 8; ++j4) {
    float tv[4];
#pragma unroll
    for (int c = 0; c < 4; ++c) {
      int j = jb + j4*4 + c;
      float v = b2[j];
#pragma unroll
      for (int kk = 0; kk < MLP_H; ++kk) v += m1[kk] * w2[kk*HID + j];
      tv[c] = fmaxf(v, 0.f);
    }
    float4 o = {tv[0], tv[1], tv[2], tv[3]};
    *reinterpret_cast<float4*>(tu + i * HID + jb + j4*4) = o;
  }
}

// -------------------- column stats (sum, sumsq), feature-per-lane --------------------
template <int NF>
__global__ __launch_bounds__(TPB) void k_colstats(const float* __restrict__ X,
                                                  int nrows, float* __restrict__ gstat) {
  const int RPB = TPB / NF;
  int f = threadIdx.x % NF;
  int rloc = threadIdx.x / NF;
  float s = 0.f, q = 0.f;
  for (int r = blockIdx.x * RPB + rloc; r < nrows; r += gridDim.x * RPB) {
    float v = X[r * NF + f];
    s += v; q = fmaf(v, v, q);
  }
  __shared__ float ls[TPB], lq[TPB];
  ls[threadIdx.x] = s; lq[threadIdx.x] = q;
  __syncthreads();
  if (threadIdx.x < NF) {
    float ss = 0.f, qq = 0.f;
#pragma unroll
    for (int r = 0; r < RPB; ++r) { ss += ls[r*NF + f]; qq += lq[r*NF + f]; }
    unsafeAtomicAdd(&gstat[f], ss);
    unsafeAtomicAdd(&gstat[NF + f], qq);
  }
}

// -------------------- residual (BNu2 coefs inline via LDS) --------------------
__global__ __launch_bounds__(TPB) void k_resid(float* __restrict__ h,
                                               const float* __restrict__ tu,
                                               const float* __restrict__ gstat_in, // tu stats (N count)
                                               const float* __restrict__ gu2,
                                               const float* __restrict__ beu2) {
  __shared__ float sa[HID], sc[HID];
  {
    int t = threadIdx.x;
    if (t < HID) {
      float mu = gstat_in[t] * (1.f / N_NODES);
      float var = fmaxf(gstat_in[HID + t] * (1.f / N_NODES) - mu * mu, 0.f);
      float a = gu2[t] * rsqrtf(var + EPS);
      sa[t] = a; sc[t] = beu2[t] - a * mu;
    }
  }
  __syncthreads();
  int idx = blockIdx.x * TPB + threadIdx.x;
  if (idx >= N_NODES * (HID/4)) return;
  int j0 = (idx & (HID/4 - 1)) * 4;
  float4 hv = reinterpret_cast<const float4*>(h)[idx];
  float4 tv = reinterpret_cast<const float4*>(tu)[idx];
  hv.x += sa[j0]  *tv.x + sc[j0];
  hv.y += sa[j0+1]*tv.y + sc[j0+1];
  hv.z += sa[j0+2]*tv.z + sc[j0+2];
  hv.w += sa[j0+3]*tv.w + sc[j0+3];
  reinterpret_cast<float4*>(h)[idx] = hv;
}

// -------------------- pool + head --------------------
__global__ __launch_bounds__(TPB) void k_pool_head(const float* __restrict__ h,
                                                   const int* __restrict__ batch,
                                                   const float* __restrict__ ow,
                                                   const float* __restrict__ ob,
                                                   float* __restrict__ out) {
  int g = blockIdx.x;
  int lo = 0, hi = N_NODES;
  while (lo < hi) { int mid = (lo+hi) >> 1; if (batch[mid] < g) lo = mid+1; else hi = mid; }
  int start = lo;
  lo = start; hi = N_NODES;
  while (lo < hi) { int mid = (lo+hi) >> 1; if (batch[mid] < g+1) lo = mid+1; else hi = mid; }
  int end = lo;
  int j = threadIdx.x & 63;
  int sub = threadIdx.x >> 6;
  float acc = 0.f;
  for (int n = start + sub; n < end; n += 4) acc += h[n*HID + j];
  __shared__ float red[TPB];
  red[threadIdx.x] = acc;
  __syncthreads();
  if (threadIdx.x < 64) {
    float s = red[threadIdx.x] + red[64+threadIdx.x] + red[128+threadIdx.x] + red[192+threadIdx.x];
    float cnt = (float)(end - start);
    float pooled = s / fmaxf(cnt, 1.0f);
    float v = pooled * ow[threadIdx.x];
    v = wsum(v);
    if (threadIdx.x == 0) out[g] = fmaxf(v + ob[0], 0.f);
  }
}

// -------------------- launch --------------------
extern "C" void kernel_launch(void* const* d_in, const int* in_sizes, int n_in,
                              void* d_out, int out_size, void* d_ws, size_t ws_size,
                              hipStream_t stream) {
  const float* x       = (const float*)d_in[0];
  const int*   ei      = (const int*)  d_in[1];
  const float* ea      = (const float*)d_in[2];
  const int*   batch   = (const int*)  d_in[3];
  const float* lin_w   = (const float*)d_in[4];
  const float* lin_b   = (const float*)d_in[5];
  const float* msg_w1  = (const float*)d_in[6];
  const float* msg_b1  = (const float*)d_in[7];
  const float* msg_g1  = (const float*)d_in[8];
  const float* msg_be1 = (const float*)d_in[9];
  const float* msg_w2  = (const float*)d_in[10];
  const float* msg_b2  = (const float*)d_in[11];
  const float* msg_g2  = (const float*)d_in[12];
  const float* msg_be2 = (const float*)d_in[13];
  const float* upd_w1  = (const float*)d_in[14];
  const float* upd_b1  = (const float*)d_in[15];
  const float* upd_g1  = (const float*)d_in[16];
  const float* upd_be1 = (const float*)d_in[17];
  const float* upd_w2  = (const float*)d_in[18];
  const float* upd_b2  = (const float*)d_in[19];
  const float* upd_g2  = (const float*)d_in[20];
  const float* upd_be2 = (const float*)d_in[21];
  const float* out_w   = (const float*)d_in[22];
  const float* out_b   = (const float*)d_in[23];
  float* out = (float*)d_out;

  float* W     = (float*)d_ws;
  float* h     = W;                         //  6,400,000
  float* P     = W + 6400000;               //  3,200,000
  _Float16* Qh = (_Float16*)(W + 9600000);  //  1,600,000 floats worth
  float* agg   = W + 11200000;              //  6,400,000
  _Float16* z1h = (_Float16*)(W + 17600000);//  EPAD_MAX*32 f16 + margin = 17,600,256 floats
  float* zu1   = W + 17600000;              //  alias into z1h span (dead by then)
  float* tu    = W + 20800000;              //  alias into z1h span
  float* stats = W + 35200512;              //  3*384
  int*   ib    = (int*)(W + 35201664);
  int* deg       = ib;                      //   100,000
  int* rs_pad    = ib + 100000;             //   100,001
  int* cursor    = ib + 200001;             //   100,000
  int* partials  = ib + 300001;             //   NCHUNK (<128)
  int* nmap      = ib + 300136;             //   NMAP_MAX = 275,008
  i32x4* erec    = (i32x4*)(ib + 575148);   //   EPAD_MAX x int4 (16B aligned: 575148%4==0)

  hipMemsetAsync(stats, 0, 3*384*sizeof(float), stream);
  hipMemsetAsync(deg, 0, N_NODES*sizeof(int), stream);
  hipMemsetAsync(nmap, 0, NMAP_MAX*sizeof(int), stream);

  // padded CSR build
  k_deg<<<N_EDGES/TPB, TPB, 0, stream>>>(ei, deg);
  k_scan_part<<<NCHUNK, SCAN_B, 0, stream>>>(deg, partials);
  k_scan_mid<<<1, 1, 0, stream>>>(partials, rs_pad);
  k_scan_fin<<<NCHUNK, SCAN_B, 0, stream>>>(deg, partials, rs_pad, cursor);
  k_fill<<<N_EDGES/TPB, TPB, 0, stream>>>(ei, ea, cursor, erec);
  k_pad<<<(N_NODES+TPB-1)/TPB, TPB, 0, stream>>>(deg, rs_pad, erec, nmap);

  k_lin_in<<<(N_NODES+TPB-1)/TPB, TPB, 0, stream>>>(x, lin_w, lin_b, h);

  const int PQ_BLKS  = NODEBLKS;             // 1563
  const int UPD_BLKS = (NODEBLKS + 1) / 2;   // 782

  for (int l = 0; l < 3; ++l) {
    const float* mw1 = msg_w1 + (size_t)l*129*MLP_H;
    const float* mb1 = msg_b1 + l*MLP_H;
    const float* mg1 = msg_g1 + l*MLP_H;
    const float* mbe1= msg_be1 + l*MLP_H;
    const float* mw2 = msg_w2 + (size_t)l*MLP_H*HID;
    const float* mb2 = msg_b2 + l*HID;
    const float* mg2 = msg_g2 + l*HID;
    const float* mbe2= msg_be2 + l*HID;
    const float* uw1 = upd_w1 + (size_t)l*128*MLP_H;
    const float* ub1 = upd_b1 + l*MLP_H;
    const float* ug1 = upd_g1 + l*MLP_H;
    const float* ube1= upd_be1 + l*MLP_H;
    const float* uw2 = upd_w2 + (size_t)l*MLP_H*HID;
    const float* ub2 = upd_b2 + l*HID;
    const float* ug2 = upd_g2 + l*HID;
    const float* ube2= upd_be2 + l*HID;
    float* st = stats + l*384;   // [0:64) BN1 | [64:192) t | [192:256) zu1 | [256:384) tu

    hipMemsetAsync(agg, 0, (size_t)N_NODES*HID*sizeof(float), stream);
    k_pq<<<PQ_BLKS, TPB, 0, stream>>>(h, mw1, mb1, P, Qh);
    k_gather<<<GSB, TPB, 0, stream>>>(P, Qh, erec, mw1, rs_pad, z1h, st);
    k_msgdot<<<GSB, TPB, 0, stream>>>(z1h, nmap, rs_pad, st, mg1, mbe1, mw2, mb2,
                                      agg, st+64);
    k_upd1<<<UPD_BLKS, TPB, 0, stream>>>(h, agg, deg, st+64, mg2, mbe2, uw1, ub1, zu1);
    k_colstats<MLP_H><<<512, TPB, 0, stream>>>(zu1, N_NODES, st+192);
    k_upd2<<<UPD_BLKS, TPB, 0, stream>>>(zu1, st+192, ug1, ube1, uw2, ub2, tu);
    k_colstats<HID><<<512, TPB, 0, stream>>>(tu, N_NODES, st+256);
    k_resid<<<(N_NODES*(HID/4)+TPB-1)/TPB, TPB, 0, stream>>>(h, tu, st+256, ug2, ube2);
  }

  k_pool_head<<<NUM_GRAPHS, TPB, 0, stream>>>(h, batch, out_w, out_b, out);
}

// Round 12
// 943.669 us; speedup vs baseline: 1.2978x; 1.2978x over previous
//
#include <hip/hip_runtime.h>
#include <hip/hip_bf16.h>

#define N_NODES   100000
#define N_EDGES   800000
#define NUM_GRAPHS 512
#define IN_DIM    16
#define HID       64
#define MLP_H     32
#define EPS       1e-5f
#define TPB       256
#define SCAN_B    1024
#define NCHUNK    ((N_NODES + SCAN_B - 1) / SCAN_B)   // 98
#define GSB       2048
#define NWAVES    (GSB * 4)                           // 8192
#define PER_W     ((N_EDGES + NWAVES - 1) / NWAVES)   // 98 edges per wave
#define NODEBLKS  ((N_NODES + 63) / 64)               // 1563

using nh2   = decltype(__builtin_amdgcn_cvt_pkrtz(0.f, 0.f));  // packed 2x f16
typedef _Float16 f16x8 __attribute__((ext_vector_type(8)));
typedef float    f32x4 __attribute__((ext_vector_type(4)));
typedef int      i32x4 __attribute__((ext_vector_type(4)));

__device__ __forceinline__ nh2 pack2(float a, float b) {
  return __builtin_amdgcn_cvt_pkrtz(a, b);
}
__device__ __forceinline__ float wsum(float v) {
  v += __shfl_xor(v, 1, 64);
  v += __shfl_xor(v, 2, 64);
  v += __shfl_xor(v, 4, 64);
  v += __shfl_xor(v, 8, 64);
  v += __shfl_xor(v, 16, 64);
  v += __shfl_xor(v, 32, 64);
  return v;
}
__device__ __forceinline__ int lbound(const int* __restrict__ rs, int key) {
  int lo = 0, hi = N_NODES;
  while (lo < hi) { int m = (lo + hi) >> 1; if (rs[m] < key) lo = m + 1; else hi = m; }
  return lo;
}

// -------------------- CSR build --------------------
__global__ __launch_bounds__(TPB) void k_deg(const int* __restrict__ ei, int* __restrict__ deg) {
  int e = blockIdx.x * TPB + threadIdx.x;
  if (e < N_EDGES) atomicAdd(&deg[ei[N_EDGES + e]], 1);
}

__global__ __launch_bounds__(SCAN_B) void k_scan_part(const int* __restrict__ deg,
                                                      int* __restrict__ partials) {
  __shared__ int red[SCAN_B];
  int i = blockIdx.x * SCAN_B + threadIdx.x;
  red[threadIdx.x] = (i < N_NODES) ? deg[i] : 0;
  __syncthreads();
  for (int off = SCAN_B / 2; off > 0; off >>= 1) {
    if (threadIdx.x < off) red[threadIdx.x] += red[threadIdx.x + off];
    __syncthreads();
  }
  if (threadIdx.x == 0) partials[blockIdx.x] = red[0];
}

__global__ void k_scan_mid(int* __restrict__ partials, int* __restrict__ row_start) {
  int run = 0;
  for (int b = 0; b < NCHUNK; ++b) { int t = partials[b]; partials[b] = run; run += t; }
  row_start[N_NODES] = run;  // == N_EDGES
}

__global__ __launch_bounds__(SCAN_B) void k_scan_fin(const int* __restrict__ deg,
                                                     const int* __restrict__ partials,
                                                     int* __restrict__ row_start,
                                                     int* __restrict__ cursor) {
  __shared__ int buf[2][SCAN_B];
  int t = threadIdx.x, i = blockIdx.x * SCAN_B + t;
  int v = (i < N_NODES) ? deg[i] : 0;
  buf[0][t] = v;
  __syncthreads();
  int cur = 0;
  for (int off = 1; off < SCAN_B; off <<= 1) {
    int nv = buf[cur][t] + ((t >= off) ? buf[cur][t - off] : 0);
    buf[cur ^ 1][t] = nv; cur ^= 1;
    __syncthreads();
  }
  if (i < N_NODES) {
    int excl = buf[cur][t] - v + partials[blockIdx.x];
    row_start[i] = excl;
    cursor[i] = excl;
  }
}

// fill packed edge records {src, dst, ea_bits, 0}, sorted by dst
__global__ __launch_bounds__(TPB) void k_fill(const int* __restrict__ ei,
                                              const float* __restrict__ ea,
                                              int* __restrict__ cursor,
                                              i32x4* __restrict__ erec) {
  int e = blockIdx.x * TPB + threadIdx.x;
  if (e >= N_EDGES) return;
  int dst = ei[N_EDGES + e];
  int pos = atomicAdd(&cursor[dst], 1);
  i32x4 rec;
  rec[0] = ei[e];
  rec[1] = dst;
  rec[2] = __float_as_int(ea[e]);
  rec[3] = 0;
  erec[pos] = rec;
}

// -------------------- input projection --------------------
__global__ __launch_bounds__(TPB) void k_lin_in(const float* __restrict__ x,
                                                const float* __restrict__ w,
                                                const float* __restrict__ b,
                                                float* __restrict__ h) {
  int i = blockIdx.x * TPB + threadIdx.x;
  if (i >= N_NODES) return;
  float xi[IN_DIM];
  const float4* xp = reinterpret_cast<const float4*>(x + i * IN_DIM);
#pragma unroll
  for (int q = 0; q < 4; ++q) {
    float4 v = xp[q];
    xi[4*q] = v.x; xi[4*q+1] = v.y; xi[4*q+2] = v.z; xi[4*q+3] = v.w;
  }
  float4* hp = reinterpret_cast<float4*>(h + i * HID);
#pragma unroll
  for (int j4 = 0; j4 < HID/4; ++j4) {
    float o[4];
#pragma unroll
    for (int c = 0; c < 4; ++c) {
      int j = j4*4 + c;
      float acc = b[j];
#pragma unroll
      for (int k = 0; k < IN_DIM; ++k) acc += xi[k] * w[k*HID + j];
      o[c] = acc;
    }
    float4 ov = {o[0], o[1], o[2], o[3]};
    hp[j4] = ov;
  }
}

// -------------------- per-node msg projections, 4-way scalar-part split ---------------
// parts 0,1: P halves -> Ph (f16); parts 2,3: Q halves -> Qh (f16)
__global__ __launch_bounds__(TPB) void k_pq(const float* __restrict__ h,
                                            const float* __restrict__ w1,
                                            const float* __restrict__ b1,
                                            _Float16* __restrict__ Ph,
                                            _Float16* __restrict__ Qh) {
  const int part = __builtin_amdgcn_readfirstlane(threadIdx.x >> 6);  // SGPR
  const int lane = threadIdx.x & 63;
  const int i = blockIdx.x * 64 + lane;
  if (i >= N_NODES) return;
  const int jb = (part & 1) * 16;
  const bool isQ = part >= 2;
  const float* wbase = w1 + (isQ ? 64 * MLP_H : 0) + jb;
  float acc[16];
#pragma unroll
  for (int j = 0; j < 16; ++j) acc[j] = isQ ? 0.f : b1[jb + j];
  const float4* hp = reinterpret_cast<const float4*>(h + i * HID);
#pragma unroll 4
  for (int k4 = 0; k4 < 16; ++k4) {
    float4 a = hp[k4];
    const float* wr = wbase + (k4*4) * MLP_H;
#pragma unroll
    for (int j = 0; j < 16; ++j)
      acc[j] += a.x*wr[j] + a.y*wr[MLP_H+j] + a.z*wr[2*MLP_H+j] + a.w*wr[3*MLP_H+j];
  }
  _Float16* dst = isQ ? Qh : Ph;
  i32x4 o0, o1;
#pragma unroll
  for (int c = 0; c < 4; ++c) {
    o0[c] = __builtin_bit_cast(int, pack2(acc[2*c],   acc[2*c+1]));
    o1[c] = __builtin_bit_cast(int, pack2(acc[8+2*c], acc[8+2*c+1]));
  }
  i32x4* qp = reinterpret_cast<i32x4*>(dst + i * MLP_H + jb);
  qp[0] = o0; qp[1] = o1;
}

// -------------------- pass 1: gather + z compute + z1(f16) store + BN1 stats ----------
// Quarter-wave layout: 16 lanes per edge, lane handles feature pair (2kq, 2kq+1).
// 4 edges per round; 3-stage pipeline (rec 3 ahead, Q/P data 2 ahead). P is f16 now.
__global__ __launch_bounds__(TPB) void k_gather(const _Float16* __restrict__ Ph,
                                                const _Float16* __restrict__ Qh,
                                                const i32x4* __restrict__ erec,
                                                const float* __restrict__ w1,
                                                _Float16* __restrict__ z1h,
                                                float* __restrict__ gstat) {
  const int lane = threadIdx.x & 63;
  const int kq  = lane & 15;      // feature pair index
  const int qtr = lane >> 4;      // quarter = edge slot within round
  const float wk0 = w1[128 * MLP_H + 2*kq];
  const float wk1 = w1[128 * MLP_H + 2*kq + 1];
  const int* Qi = (const int*)Qh;
  const int* Pi = (const int*)Ph;
  int* z1i = (int*)z1h;
  float s0 = 0.f, s1 = 0.f, qa0 = 0.f, qa1 = 0.f;
  const int wv = blockIdx.x * 4 + (threadIdx.x >> 6);
  const int c0 = wv * PER_W;
  const int c1 = min(c0 + PER_W, N_EDGES);
  if (c0 < N_EDGES) {
    const int c1m1 = c1 - 1;
    const int rounds = (c1 - c0 + 3) >> 2;
#define EIDX(R) min(c0 + 4*(R) + qtr, c1m1)
    i32x4 rec2 = erec[EIDX(0)];
    i32x4 rec3 = erec[EIDX(1)];
    i32x4 recH = erec[EIDX(2)];
    int   qiA = Qi[rec2[0] * 16 + kq];
    int   piA = Pi[rec2[1] * 16 + kq];
    float aA  = __int_as_float(rec2[2]);
    int   qiB = Qi[rec3[0] * 16 + kq];
    int   piB = Pi[rec3[1] * 16 + kq];
    float aB  = __int_as_float(rec3[2]);
    for (int r = 0; r < rounds; ++r) {
      i32x4 recN = erec[EIDX(r + 3)];
      int   qiC = Qi[recH[0] * 16 + kq];
      int   piC = Pi[recH[1] * 16 + kq];
      float aC  = __int_as_float(recH[2]);
      const int e = c0 + 4*r + qtr;
      nh2 hv = __builtin_bit_cast(nh2, qiA);
      nh2 pv = __builtin_bit_cast(nh2, piA);
      float z0 = (float)pv.x + (float)hv.x + aA * wk0;
      float z1 = (float)pv.y + (float)hv.y + aA * wk1;
      if (e < c1) {
        z1i[min(e, c1m1) * 16 + kq] = __builtin_bit_cast(int, pack2(z0, z1));
        s0 += z0; s1 += z1;
        qa0 = fmaf(z0, z0, qa0); qa1 = fmaf(z1, z1, qa1);
      }
      qiA = qiB; piA = piB; aA = aB;
      qiB = qiC; piB = piC; aB = aC;
      recH = recN;
    }
#undef EIDX
  }
  // reduce across quarters (same feature pair in lanes with equal kq)
  s0  += __shfl_xor(s0, 16, 64);  s0  += __shfl_xor(s0, 32, 64);
  s1  += __shfl_xor(s1, 16, 64);  s1  += __shfl_xor(s1, 32, 64);
  qa0 += __shfl_xor(qa0, 16, 64); qa0 += __shfl_xor(qa0, 32, 64);
  qa1 += __shfl_xor(qa1, 16, 64); qa1 += __shfl_xor(qa1, 32, 64);
  __shared__ float ls[4][MLP_H], lq[4][MLP_H];
  const int w = threadIdx.x >> 6;
  if (lane < 16) {
    ls[w][2*lane] = s0; ls[w][2*lane+1] = s1;
    lq[w][2*lane] = qa0; lq[w][2*lane+1] = qa1;
  }
  __syncthreads();
  const int t = threadIdx.x;
  if (t < MLP_H)
    unsafeAtomicAdd(&gstat[t], ls[0][t] + ls[1][t] + ls[2][t] + ls[3][t]);
  else if (t < 2*MLP_H)
    unsafeAtomicAdd(&gstat[t], lq[0][t-MLP_H] + lq[1][t-MLP_H] + lq[2][t-MLP_H] + lq[3][t-MLP_H]);
}

// -------------------- pass 2: MFMA msg2 + aggregate + t-stats --------------------
// Per-node 16-edge tiles over linear z1h; cross-node 1-deep zv prefetch.
__global__ __launch_bounds__(TPB) void k_msgdot(const _Float16* __restrict__ z1h,
                                                const int* __restrict__ rs,
                                                const float* __restrict__ gstat_in, // BN1 stats
                                                const float* __restrict__ g1,
                                                const float* __restrict__ be1,
                                                const float* __restrict__ w2,
                                                const float* __restrict__ b2,
                                                float* __restrict__ agg,
                                                float* __restrict__ gstat_out) {
  const int lane = threadIdx.x & 63;
  const int col = lane & 15;
  const int g   = lane >> 4;
  float a1v[8], c1v[8];
#pragma unroll
  for (int i = 0; i < 8; ++i) {
    int kf = g*8 + i;
    float mu = gstat_in[kf] * (1.f / N_EDGES);
    float var = fmaxf(gstat_in[MLP_H + kf] * (1.f / N_EDGES) - mu * mu, 0.f);
    float a = g1[kf] * rsqrtf(var + EPS);
    a1v[i] = a; c1v[i] = be1[kf] - a * mu;
  }
  f16x8 bf0, bf1, bf2, bf3;
#define MKB(BF, C) { i32x4 bw; \
  _Pragma("unroll") for (int ii = 0; ii < 4; ++ii) { \
    nh2 p = pack2(w2[(g*8 + 2*ii) * HID + (C)*16 + col], \
                  w2[(g*8 + 2*ii + 1) * HID + (C)*16 + col]); \
    bw[ii] = __builtin_bit_cast(int, p); } \
  BF = __builtin_bit_cast(f16x8, bw); }
  MKB(bf0, 0) MKB(bf1, 1) MKB(bf2, 2) MKB(bf3, 3)
#undef MKB
  float b2c[4];
#pragma unroll
  for (int c = 0; c < 4; ++c) b2c[c] = b2[c*16 + col];

  float sacc[4] = {0.f,0.f,0.f,0.f}, qacc[4] = {0.f,0.f,0.f,0.f};
  const int wv = blockIdx.x * 4 + (threadIdx.x >> 6);
  const int key0 = min(wv * PER_W, N_EDGES);
  const int key1 = min((wv + 1) * PER_W, N_EDGES);
  const int n0 = lbound(rs, key0);
  const int n1 = (wv == NWAVES - 1) ? N_NODES : lbound(rs, key1);

  if (n0 < n1) {
    const int eLast = rs[n1] - 1;
    // prefetch first tile's z rows
    f16x8 zv = *reinterpret_cast<const f16x8*>(z1h + min(rs[n0] + col, eLast) * MLP_H + g * 8);
    for (int n = n0; n < n1; ++n) {
      const int start = rs[n], end = rs[n + 1];
      float aggacc[4] = {0.f,0.f,0.f,0.f};
      for (int t0 = start; t0 < end; t0 += 16) {
        // prefetch next tile (within node or next node's start), clamped to wave range
        const int bnext = (t0 + 16 < end) ? (t0 + 16) : end;
        f16x8 zvN = *reinterpret_cast<const f16x8*>(z1h + min(bnext + col, eLast) * MLP_H + g * 8);
        // A-prep from current zv
        i32x4 aw;
#pragma unroll
        for (int i = 0; i < 4; ++i) {
          float m0 = fmaxf(fmaf(a1v[2*i],   (float)zv[2*i],   c1v[2*i]),   0.f);
          float m1 = fmaxf(fmaf(a1v[2*i+1], (float)zv[2*i+1], c1v[2*i+1]), 0.f);
          aw[i] = __builtin_bit_cast(int, pack2(m0, m1));
        }
        f16x8 af = __builtin_bit_cast(f16x8, aw);
        f32x4 zc = {0.f,0.f,0.f,0.f};
        f32x4 cc0 = __builtin_amdgcn_mfma_f32_16x16x32_f16(af, bf0, zc, 0, 0, 0);
        f32x4 cc1 = __builtin_amdgcn_mfma_f32_16x16x32_f16(af, bf1, zc, 0, 0, 0);
        f32x4 cc2 = __builtin_amdgcn_mfma_f32_16x16x32_f16(af, bf2, zc, 0, 0, 0);
        f32x4 cc3 = __builtin_amdgcn_mfma_f32_16x16x32_f16(af, bf3, zc, 0, 0, 0);
        bool vld[4];
#pragma unroll
        for (int reg = 0; reg < 4; ++reg) vld[reg] = (t0 + g*4 + reg) < end;
#define EPI(CC, CI) { \
  _Pragma("unroll") for (int reg = 0; reg < 4; ++reg) { \
    float tv = fmaxf(CC[reg] + b2c[CI], 0.f); \
    tv = vld[reg] ? tv : 0.f; \
    aggacc[CI] += tv; qacc[CI] = fmaf(tv, tv, qacc[CI]); } }
        EPI(cc0, 0) EPI(cc1, 1) EPI(cc2, 2) EPI(cc3, 3)
#undef EPI
        zv = zvN;
      }
#pragma unroll
      for (int c = 0; c < 4; ++c) sacc[c] += aggacc[c];
#pragma unroll
      for (int c = 0; c < 4; ++c) {
        aggacc[c] += __shfl_xor(aggacc[c], 16, 64);
        aggacc[c] += __shfl_xor(aggacc[c], 32, 64);
      }
      float aout = (g == 0) ? aggacc[0] : (g == 1) ? aggacc[1] : (g == 2) ? aggacc[2] : aggacc[3];
      agg[n * HID + g * 16 + col] = aout;
    }
  }
#pragma unroll
  for (int c = 0; c < 4; ++c) {
    sacc[c] += __shfl_xor(sacc[c], 16, 64);
    sacc[c] += __shfl_xor(sacc[c], 32, 64);
    qacc[c] += __shfl_xor(qacc[c], 16, 64);
    qacc[c] += __shfl_xor(qacc[c], 32, 64);
  }
  __shared__ float ls[4][HID], lq[4][HID];
  const int w = threadIdx.x >> 6;
  if (g == 0) {
#pragma unroll
    for (int c = 0; c < 4; ++c) { ls[w][c*16 + col] = sacc[c]; lq[w][c*16 + col] = qacc[c]; }
  }
  __syncthreads();
  const int t = threadIdx.x;
  if (t < HID)
    unsafeAtomicAdd(&gstat_out[t], ls[0][t] + ls[1][t] + ls[2][t] + ls[3][t]);
  else if (t < 2*HID)
    unsafeAtomicAdd(&gstat_out[t], lq[0][t-HID] + lq[1][t-HID] + lq[2][t-HID] + lq[3][t-HID]);
}

// -------------------- update stage 1, 2-way scalar-part split (no stats) --------------
__global__ __launch_bounds__(TPB) void k_upd1(const float* __restrict__ h,
                                              const float* __restrict__ agg,
                                              const int* __restrict__ deg,
                                              const float* __restrict__ gstat_in, // t stats (E count)
                                              const float* __restrict__ g2,
                                              const float* __restrict__ be2,
                                              const float* __restrict__ w1,
                                              const float* __restrict__ b1,
                                              float* __restrict__ zu1) {
  __shared__ float sa[HID], sc[HID];
  {
    int t = threadIdx.x;
    if (t < HID) {
      float mu = gstat_in[t] * (1.f / N_EDGES);
      float var = fmaxf(gstat_in[HID + t] * (1.f / N_EDGES) - mu * mu, 0.f);
      float a = g2[t] * rsqrtf(var + EPS);
      sa[t] = a; sc[t] = be2[t] - a * mu;
    }
  }
  __syncthreads();
  const int widx = __builtin_amdgcn_readfirstlane(threadIdx.x >> 6);  // SGPR
  const int part = widx & 1;
  const int grp  = blockIdx.x * 2 + (widx >> 1);
  const int lane = threadIdx.x & 63;
  const int jb = part * 16;
  const int i = grp * 64 + lane;
  if (i >= N_NODES) return;
  float acc[16];
#pragma unroll
  for (int j = 0; j < 16; ++j) acc[j] = b1[jb + j];
  const float4* hp = reinterpret_cast<const float4*>(h + i * HID);
#pragma unroll 4
  for (int k4 = 0; k4 < 16; ++k4) {
    float4 a = hp[k4];
    const float* wr = w1 + (k4*4) * MLP_H + jb;
#pragma unroll
    for (int j = 0; j < 16; ++j)
      acc[j] += a.x*wr[j] + a.y*wr[MLP_H+j] + a.z*wr[2*MLP_H+j] + a.w*wr[3*MLP_H+j];
  }
  float degf = (float)deg[i];
  const float4* ap = reinterpret_cast<const float4*>(agg + i * HID);
#pragma unroll 4
  for (int k4 = 0; k4 < 16; ++k4) {
    float4 g4 = ap[k4];
    int k = k4*4;
    float a0 = sa[k]  *g4.x + sc[k]  *degf;
    float a1 = sa[k+1]*g4.y + sc[k+1]*degf;
    float a2 = sa[k+2]*g4.z + sc[k+2]*degf;
    float a3 = sa[k+3]*g4.w + sc[k+3]*degf;
    const float* wr = w1 + (64 + k) * MLP_H + jb;
#pragma unroll
    for (int j = 0; j < 16; ++j)
      acc[j] += a0*wr[j] + a1*wr[MLP_H+j] + a2*wr[2*MLP_H+j] + a3*wr[3*MLP_H+j];
  }
  float4* zp = reinterpret_cast<float4*>(zu1 + i * MLP_H + jb);
#pragma unroll
  for (int c = 0; c < 4; ++c) {
    float4 o = {acc[4*c], acc[4*c+1], acc[4*c+2], acc[4*c+3]};
    zp[c] = o;
  }
}

// -------------------- update stage 2, 2-way scalar-part split (no stats) --------------
__global__ __launch_bounds__(TPB) void k_upd2(const float* __restrict__ zu1,
                                              const float* __restrict__ gstat_in, // zu1 stats (N count)
                                              const float* __restrict__ gu1,
                                              const float* __restrict__ beu1,
                                              const float* __restrict__ w2,
                                              const float* __restrict__ b2,
                                              float* __restrict__ tu) {
  __shared__ float sa[MLP_H], sc[MLP_H];
  {
    int t = threadIdx.x;
    if (t < MLP_H) {
      float mu = gstat_in[t] * (1.f / N_NODES);
      float var = fmaxf(gstat_in[MLP_H + t] * (1.f / N_NODES) - mu * mu, 0.f);
      float a = gu1[t] * rsqrtf(var + EPS);
      sa[t] = a; sc[t] = beu1[t] - a * mu;
    }
  }
  __syncthreads();
  const int widx = __builtin_amdgcn_readfirstlane(threadIdx.x >> 6);  // SGPR
  const int part = widx & 1;
  const int grp  = blockIdx.x * 2 + (widx >> 1);
  const int lane = threadIdx.x & 63;
  const int jb = part * 32;
  const int i = grp * 64 + lane;
  if (i >= N_NODES) return;
  float m1[MLP_H];
  const float4* zp = reinterpret_cast<const float4*>(zu1 + i * MLP_H);
#pragma unroll
  for (int c = 0; c < MLP_H/4; ++c) {
    float4 z = zp[c];
    int kk = 4*c;
    m1[kk]   = fmaxf(sa[kk]  *z.x + sc[kk],   0.f);
    m1[kk+1] = fmaxf(sa[kk+1]*z.y + sc[kk+1], 0.f);
    m1[kk+2] = fmaxf(sa[kk+2]*z.z + sc[kk+2], 0.f);
    m1[kk+3] = fmaxf(sa[kk+3]*z.w + sc[kk+3], 0.f);
  }
#pragma unroll
  for (int j4 = 0; j4 < 8; ++j4) {
    float tv[4];
#pragma unroll
    for (int c = 0; c < 4; ++c) {
      int j = jb + j4*4 + c;
      float v = b2[j];
#pragma unroll
      for (int kk = 0; kk < MLP_H; ++kk) v += m1[kk] * w2[kk*HID + j];
      tv[c] = fmaxf(v, 0.f);
    }
    float4 o = {tv[0], tv[1], tv[2], tv[3]};
    *reinterpret_cast<float4*>(tu + i * HID + jb + j4*4) = o;
  }
}

// -------------------- column stats (sum, sumsq), feature-per-lane --------------------
template <int NF>
__global__ __launch_bounds__(TPB) void k_colstats(const float* __restrict__ X,
                                                  int nrows, float* __restrict__ gstat) {
  const int RPB = TPB / NF;
  int f = threadIdx.x % NF;
  int rloc = threadIdx.x / NF;
  float s = 0.f, q = 0.f;
  for (int r = blockIdx.x * RPB + rloc; r < nrows; r += gridDim.x * RPB) {
    float v = X[r * NF + f];
    s += v; q = fmaf(v, v, q);
  }
  __shared__ float ls[TPB], lq[TPB];
  ls[threadIdx.x] = s; lq[threadIdx.x] = q;
  __syncthreads();
  if (threadIdx.x < NF) {
    float ss = 0.f, qq = 0.f;
#pragma unroll
    for (int r = 0; r < RPB; ++r) { ss += ls[r*NF + f]; qq += lq[r*NF + f]; }
    unsafeAtomicAdd(&gstat[f], ss);
    unsafeAtomicAdd(&gstat[NF + f], qq);
  }
}

// -------------------- residual (BNu2 coefs inline via LDS) --------------------
__global__ __launch_bounds__(TPB) void k_resid(float* __restrict__ h,
                                               const float* __restrict__ tu,
                                               const float* __restrict__ gstat_in, // tu stats (N count)
                                               const float* __restrict__ gu2,
                                               const float* __restrict__ beu2) {
  __shared__ float sa[HID], sc[HID];
  {
    int t = threadIdx.x;
    if (t < HID) {
      float mu = gstat_in[t] * (1.f / N_NODES);
      float var = fmaxf(gstat_in[HID + t] * (1.f / N_NODES) - mu * mu, 0.f);
      float a = gu2[t] * rsqrtf(var + EPS);
      sa[t] = a; sc[t] = beu2[t] - a * mu;
    }
  }
  __syncthreads();
  int idx = blockIdx.x * TPB + threadIdx.x;
  if (idx >= N_NODES * (HID/4)) return;
  int j0 = (idx & (HID/4 - 1)) * 4;
  float4 hv = reinterpret_cast<const float4*>(h)[idx];
  float4 tv = reinterpret_cast<const float4*>(tu)[idx];
  hv.x += sa[j0]  *tv.x + sc[j0];
  hv.y += sa[j0+1]*tv.y + sc[j0+1];
  hv.z += sa[j0+2]*tv.z + sc[j0+2];
  hv.w += sa[j0+3]*tv.w + sc[j0+3];
  reinterpret_cast<float4*>(h)[idx] = hv;
}

// -------------------- pool + head --------------------
__global__ __launch_bounds__(TPB) void k_pool_head(const float* __restrict__ h,
                                                   const int* __restrict__ batch,
                                                   const float* __restrict__ ow,
                                                   const float* __restrict__ ob,
                                                   float* __restrict__ out) {
  int g = blockIdx.x;
  int lo = 0, hi = N_NODES;
  while (lo < hi) { int mid = (lo+hi) >> 1; if (batch[mid] < g) lo = mid+1; else hi = mid; }
  int start = lo;
  lo = start; hi = N_NODES;
  while (lo < hi) { int mid = (lo+hi) >> 1; if (batch[mid] < g+1) lo = mid+1; else hi = mid; }
  int end = lo;
  int j = threadIdx.x & 63;
  int sub = threadIdx.x >> 6;
  float acc = 0.f;
  for (int n = start + sub; n < end; n += 4) acc += h[n*HID + j];
  __shared__ float red[TPB];
  red[threadIdx.x] = acc;
  __syncthreads();
  if (threadIdx.x < 64) {
    float s = red[threadIdx.x] + red[64+threadIdx.x] + red[128+threadIdx.x] + red[192+threadIdx.x];
    float cnt = (float)(end - start);
    float pooled = s / fmaxf(cnt, 1.0f);
    float v = pooled * ow[threadIdx.x];
    v = wsum(v);
    if (threadIdx.x == 0) out[g] = fmaxf(v + ob[0], 0.f);
  }
}

// -------------------- launch --------------------
extern "C" void kernel_launch(void* const* d_in, const int* in_sizes, int n_in,
                              void* d_out, int out_size, void* d_ws, size_t ws_size,
                              hipStream_t stream) {
  const float* x       = (const float*)d_in[0];
  const int*   ei      = (const int*)  d_in[1];
  const float* ea      = (const float*)d_in[2];
  const int*   batch   = (const int*)  d_in[3];
  const float* lin_w   = (const float*)d_in[4];
  const float* lin_b   = (const float*)d_in[5];
  const float* msg_w1  = (const float*)d_in[6];
  const float* msg_b1  = (const float*)d_in[7];
  const float* msg_g1  = (const float*)d_in[8];
  const float* msg_be1 = (const float*)d_in[9];
  const float* msg_w2  = (const float*)d_in[10];
  const float* msg_b2  = (const float*)d_in[11];
  const float* msg_g2  = (const float*)d_in[12];
  const float* msg_be2 = (const float*)d_in[13];
  const float* upd_w1  = (const float*)d_in[14];
  const float* upd_b1  = (const float*)d_in[15];
  const float* upd_g1  = (const float*)d_in[16];
  const float* upd_be1 = (const float*)d_in[17];
  const float* upd_w2  = (const float*)d_in[18];
  const float* upd_b2  = (const float*)d_in[19];
  const float* upd_g2  = (const float*)d_in[20];
  const float* upd_be2 = (const float*)d_in[21];
  const float* out_w   = (const float*)d_in[22];
  const float* out_b   = (const float*)d_in[23];
  float* out = (float*)d_out;

  float* W     = (float*)d_ws;
  float* h     = W;                        //  6,400,000
  _Float16* Ph = (_Float16*)(W + 6400000); //  1,600,000 floats worth (f16)
  _Float16* Qh = (_Float16*)(W + 9600000); //  1,600,000 floats worth (f16)
  float* agg   = W + 12800000;             //  6,400,000
  _Float16* z1h = (_Float16*)(W + 19200000); // 12,800,000 floats worth (f16)
  float* zu1   = W + 32000000;             //  3,200,000
  float* tu    = W + 35200000;             //  6,400,000
  float* stats = W + 41600000;             //  3*384
  int*   ib    = (int*)(W + 41601152);
  int* deg       = ib;                     //   100,000
  int* row_start = ib + 100000;            //   100,001
  int* cursor    = ib + 200001;            //   100,000
  int* partials  = ib + 300001;            //   NCHUNK (<=128)
  i32x4* erec    = (i32x4*)(ib + 300232);  //   800,000 x int4 (16B aligned)

  hipMemsetAsync(stats, 0, 3*384*sizeof(float), stream);
  hipMemsetAsync(deg, 0, N_NODES*sizeof(int), stream);

  // CSR build
  k_deg<<<N_EDGES/TPB, TPB, 0, stream>>>(ei, deg);
  k_scan_part<<<NCHUNK, SCAN_B, 0, stream>>>(deg, partials);
  k_scan_mid<<<1, 1, 0, stream>>>(partials, row_start);
  k_scan_fin<<<NCHUNK, SCAN_B, 0, stream>>>(deg, partials, row_start, cursor);
  k_fill<<<N_EDGES/TPB, TPB, 0, stream>>>(ei, ea, cursor, erec);

  k_lin_in<<<(N_NODES+TPB-1)/TPB, TPB, 0, stream>>>(x, lin_w, lin_b, h);

  const int PQ_BLKS  = NODEBLKS;             // 1563 (4 waves = 4 parts, 1 group)
  const int UPD_BLKS = (NODEBLKS + 1) / 2;   // 782  (4 waves = 2 groups x 2 parts)

  for (int l = 0; l < 3; ++l) {
    const float* mw1 = msg_w1 + (size_t)l*129*MLP_H;
    const float* mb1 = msg_b1 + l*MLP_H;
    const float* mg1 = msg_g1 + l*MLP_H;
    const float* mbe1= msg_be1 + l*MLP_H;
    const float* mw2 = msg_w2 + (size_t)l*MLP_H*HID;
    const float* mb2 = msg_b2 + l*HID;
    const float* mg2 = msg_g2 + l*HID;
    const float* mbe2= msg_be2 + l*HID;
    const float* uw1 = upd_w1 + (size_t)l*128*MLP_H;
    const float* ub1 = upd_b1 + l*MLP_H;
    const float* ug1 = upd_g1 + l*MLP_H;
    const float* ube1= upd_be1 + l*MLP_H;
    const float* uw2 = upd_w2 + (size_t)l*MLP_H*HID;
    const float* ub2 = upd_b2 + l*HID;
    const float* ug2 = upd_g2 + l*HID;
    const float* ube2= upd_be2 + l*HID;
    float* st = stats + l*384;   // [0:64) BN1 | [64:192) t | [192:256) zu1 | [256:384) tu

    k_pq<<<PQ_BLKS, TPB, 0, stream>>>(h, mw1, mb1, Ph, Qh);
    k_gather<<<GSB, TPB, 0, stream>>>(Ph, Qh, erec, mw1, z1h, st);
    k_msgdot<<<GSB, TPB, 0, stream>>>(z1h, row_start, st, mg1, mbe1, mw2, mb2, agg, st+64);
    k_upd1<<<UPD_BLKS, TPB, 0, stream>>>(h, agg, deg, st+64, mg2, mbe2, uw1, ub1, zu1);
    k_colstats<MLP_H><<<512, TPB, 0, stream>>>(zu1, N_NODES, st+192);
    k_upd2<<<UPD_BLKS, TPB, 0, stream>>>(zu1, st+192, ug1, ube1, uw2, ub2, tu);
    k_colstats<HID><<<512, TPB, 0, stream>>>(tu, N_NODES, st+256);
    k_resid<<<(N_NODES*(HID/4)+TPB-1)/TPB, TPB, 0, stream>>>(h, tu, st+256, ug2, ube2);
  }

  k_pool_head<<<NUM_GRAPHS, TPB, 0, stream>>>(h, batch, out_w, out_b, out);
}